// Round 1
// baseline (448.567 us; speedup 1.0000x reference)
//
#include <hip/hip_runtime.h>
#include <hip/hip_bf16.h>

// BPNN: B=512, N=2048, F=64, T=4, H1=64, H2=32.
// out[b] = sum_n MLP_{t[n]}(x[b,n,:]), MLP = silu(W0 x+b0) -> silu(W1 h+b1) -> w2.h+b2
//
// R4: latency package on top of R3's type-sorted MFMA structure.
//  - Balanced slices: each wave processes exactly SLICE consecutive atoms of
//    the type-sorted list (not "its type"), reloading weight fragments at
//    type-run boundaries (wave-uniform branch, ~1.75 reloads/wave, L2-hot).
//    Removes the ~20% multinomial max-vs-mean imbalance.
//  - Unroll-2 with dual raw-staging (rA/rB): each atom's x loads get ~2 full
//    atom-computes of latency cover instead of ~1.
//  - NCHUNK 128->64: grid 1024 blocks -> 3 blocks/CU resident (12 waves/CU,
//    3/SIMD) instead of 2 (8 waves/CU).
// MFMA orientation: D = W * x^T (A-frag == B-frag lane mapping, verified R2).

#define B_ 512
#define N_ 2048
#define F_ 64
#define T_ 4
#define H1_ 64
#define H2_ 32

#define BT 16          // b-tile (MFMA N dim)
#define WAVES 4
#define NCHUNK 64      // n per block
#define SLICE (NCHUNK / WAVES)   // 16 atoms per wave, always balanced

typedef __attribute__((ext_vector_type(8))) short bf16x8;
typedef __attribute__((ext_vector_type(4))) short bf16x4;
typedef __attribute__((ext_vector_type(4))) float f32x4;

__device__ inline float silu_f(float v) {
    return v * __builtin_amdgcn_rcpf(1.0f + __expf(-v));
}

__device__ inline bf16x8 pack8(float4 a, float4 b) {
    union { __hip_bfloat162 h[4]; bf16x8 v; } u;
    u.h[0] = __float22bfloat162_rn({a.x, a.y});
    u.h[1] = __float22bfloat162_rn({a.z, a.w});
    u.h[2] = __float22bfloat162_rn({b.x, b.y});
    u.h[3] = __float22bfloat162_rn({b.z, b.w});
    return u.v;
}

__device__ inline bf16x4 pack4(float a, float b, float c, float d) {
    union { __hip_bfloat162 h[2]; bf16x4 v; } u;
    u.h[0] = __float22bfloat162_rn({a, b});
    u.h[1] = __float22bfloat162_rn({c, d});
    return u.v;
}

__device__ inline float bf_at(bf16x4 v, int r) {
    union { bf16x4 v; __hip_bfloat16 h[4]; } u; u.v = v;
    return __bfloat162float(u.h[r]);
}

__global__ __launch_bounds__(256, 3) void bpnn_kernel(
    const float* __restrict__ x, const int* __restrict__ an,
    const float* __restrict__ w0, const float* __restrict__ b0,
    const float* __restrict__ w1, const float* __restrict__ b1,
    const float* __restrict__ w2, const float* __restrict__ b2,
    float* __restrict__ out)
{
    __shared__ __align__(16) __hip_bfloat16 trb[WAVES][BT][68]; // 8704 B transpose buf [b][h]
    __shared__ int sidx[NCHUNK];     // type-sorted, packed (type<<8)|n_local
    __shared__ int cnt[T_], pos[T_];
    __shared__ float red[BT];

    const int tid  = threadIdx.x;
    const int wave = tid >> 6;
    const int lane = tid & 63;
    const int lr   = lane & 15;      // b-col (B,C) / row (A)
    const int q    = lane >> 4;      // quad
    const int b0i  = blockIdx.y * BT;
    const int n0   = blockIdx.x * NCHUNK;

    // ---- counting sort of the block's atoms by type (type packed in idx) ----
    if (tid < T_)  cnt[tid] = 0;
    if (tid < BT)  red[tid] = 0.0f;
    __syncthreads();
    int myt = 0;
    if (tid < NCHUNK) { myt = an[n0 + tid]; atomicAdd(&cnt[myt], 1); }
    __syncthreads();
    if (tid == 0) {
        int o = 0;
        for (int k = 0; k < T_; ++k) { pos[k] = o; o += cnt[k]; }
    }
    __syncthreads();
    if (tid < NCHUNK) { int p = atomicAdd(&pos[myt], 1); sidx[p] = (myt << 8) | tid; }
    __syncthreads();

    // ---- weight fragments: reloaded on type-run boundaries (wave-uniform) ----
    bf16x8 aw0[4][2], aw1[2][2];
    bf16x4 b0f[4], b1f[2], w2f[2];
    float b2cur = 0.0f;
    int cur_t = -1;

    auto load_frags = [&](int t) {
        const float* w0t = w0 + t * (H1_ * F_);
        const float* w1t = w1 + t * (H2_ * H1_);
#pragma unroll
        for (int nt = 0; nt < 4; ++nt)
#pragma unroll
            for (int kh = 0; kh < 2; ++kh) {
                const float4* p = reinterpret_cast<const float4*>(
                    w0t + (nt * 16 + lr) * F_ + kh * 32 + q * 8);
                aw0[nt][kh] = pack8(p[0], p[1]);
            }
#pragma unroll
        for (int mt = 0; mt < 2; ++mt)
#pragma unroll
            for (int kh = 0; kh < 2; ++kh) {
                const float4* p = reinterpret_cast<const float4*>(
                    w1t + (mt * 16 + lr) * H1_ + kh * 32 + q * 8);
                aw1[mt][kh] = pack8(p[0], p[1]);
            }
#pragma unroll
        for (int nt = 0; nt < 4; ++nt) {
            float4 v = *reinterpret_cast<const float4*>(b0 + t * H1_ + nt * 16 + q * 4);
            b0f[nt] = pack4(v.x, v.y, v.z, v.w);
        }
#pragma unroll
        for (int mt = 0; mt < 2; ++mt) {
            float4 v = *reinterpret_cast<const float4*>(b1 + t * H2_ + mt * 16 + q * 4);
            b1f[mt] = pack4(v.x, v.y, v.z, v.w);
            float4 u = *reinterpret_cast<const float4*>(w2 + t * H2_ + mt * 16 + q * 4);
            w2f[mt] = pack4(u.x, u.y, u.z, u.w);
        }
        b2cur = b2[t];
    };

    const float* xb_ = x + (size_t)(b0i + lr) * (N_ * F_) + (size_t)n0 * F_ + q * 8;
    __hip_bfloat16* trbw = &trb[wave][lr][0];

    float esum0 = 0.f, esum1 = 0.f, bsum = 0.f;

    auto compute = [&](bf16x8 xf0, bf16x8 xf1) {
        // ---- layer 0: D0[64h x 16b] = W0_t * x^T ----
        f32x4 acc[4] = {{0,0,0,0},{0,0,0,0},{0,0,0,0},{0,0,0,0}};
#pragma unroll
        for (int nt = 0; nt < 4; ++nt) {
            acc[nt] = __builtin_amdgcn_mfma_f32_16x16x32_bf16(aw0[nt][0], xf0, acc[nt], 0, 0, 0);
            acc[nt] = __builtin_amdgcn_mfma_f32_16x16x32_bf16(aw0[nt][1], xf1, acc[nt], 0, 0, 0);
        }
        // bias + silu; C-layout lane holds h = nt*16 + q*4 + r, b = lr
#pragma unroll
        for (int nt = 0; nt < 4; ++nt) {
            float v0 = silu_f(acc[nt][0] + bf_at(b0f[nt], 0));
            float v1 = silu_f(acc[nt][1] + bf_at(b0f[nt], 1));
            float v2 = silu_f(acc[nt][2] + bf_at(b0f[nt], 2));
            float v3 = silu_f(acc[nt][3] + bf_at(b0f[nt], 3));
            *reinterpret_cast<bf16x4*>(trbw + nt * 16 + q * 4) = pack4(v0, v1, v2, v3);
        }
        __builtin_amdgcn_wave_barrier();  // order LDS write->read (per-wave buffer)

        bf16x8 hb0 = *reinterpret_cast<const bf16x8*>(trbw + q * 8);
        bf16x8 hb1 = *reinterpret_cast<const bf16x8*>(trbw + 32 + q * 8);
        __builtin_amdgcn_wave_barrier();

        // ---- layer 1: D1[32g x 16b] = W1_t * h1 ----
        f32x4 accB[2] = {{0,0,0,0},{0,0,0,0}};
#pragma unroll
        for (int mt = 0; mt < 2; ++mt) {
            accB[mt] = __builtin_amdgcn_mfma_f32_16x16x32_bf16(aw1[mt][0], hb0, accB[mt], 0, 0, 0);
            accB[mt] = __builtin_amdgcn_mfma_f32_16x16x32_bf16(aw1[mt][1], hb1, accB[mt], 0, 0, 0);
        }
        // ---- layer 2: lane accumulates w2[g]*silu(.) over its 8 g ----
#pragma unroll
        for (int r = 0; r < 4; ++r) {
            float v0 = silu_f(accB[0][r] + bf_at(b1f[0], r));
            esum0 += v0 * bf_at(w2f[0], r);
            float v1 = silu_f(accB[1][r] + bf_at(b1f[1], r));
            esum1 += v1 * bf_at(w2f[1], r);
        }
    };

    // ---- unroll-2 pipeline over this wave's SLICE sorted atoms ----
    const int s0 = wave * SLICE, s1 = s0 + SLICE;

    int id0 = sidx[s0];
    int id1 = sidx[s0 + 1];
    float4 rA0, rA1, rA2, rA3, rB0, rB1, rB2, rB3;
    {
        const float4* pA = reinterpret_cast<const float4*>(xb_ + (id0 & 0xFF) * F_);
        rA0 = pA[0]; rA1 = pA[1]; rA2 = pA[8]; rA3 = pA[9];
        const float4* pB = reinterpret_cast<const float4*>(xb_ + (id1 & 0xFF) * F_);
        rB0 = pB[0]; rB1 = pB[1]; rB2 = pB[8]; rB3 = pB[9];
    }

    for (int p = s0; p < s1; p += 2) {
        int pc = (p + 2 < s1) ? p + 2 : s1 - 1;   // clamp: harmless refetch at tail
        int pd = (p + 3 < s1) ? p + 3 : s1 - 1;
        int idn0 = sidx[pc];
        int idn1 = sidx[pd];

        // ---- atom A ----
        int tA = id0 >> 8;
        if (tA != cur_t) { cur_t = tA; load_frags(tA); }
        bf16x8 xf0 = pack8(rA0, rA1);             // waits on loads issued ~2 atoms ago
        bf16x8 xf1 = pack8(rA2, rA3);
        {
            const float4* pn = reinterpret_cast<const float4*>(xb_ + (idn0 & 0xFF) * F_);
            rA0 = pn[0]; rA1 = pn[1]; rA2 = pn[8]; rA3 = pn[9];
        }
        bsum += b2cur;
        compute(xf0, xf1);

        // ---- atom B ----
        int tB = id1 >> 8;
        if (tB != cur_t) { cur_t = tB; load_frags(tB); }
        bf16x8 yf0 = pack8(rB0, rB1);
        bf16x8 yf1 = pack8(rB2, rB3);
        {
            const float4* pn = reinterpret_cast<const float4*>(xb_ + (idn1 & 0xFF) * F_);
            rB0 = pn[0]; rB1 = pn[1]; rB2 = pn[8]; rB3 = pn[9];
        }
        bsum += b2cur;
        compute(yf0, yf1);

        id0 = idn0; id1 = idn1;
    }

    // reduce esum over the 4 quads holding the same b (lane bits 4-5)
    float esum = esum0 + esum1;
    esum += __shfl_xor(esum, 16);
    esum += __shfl_xor(esum, 32);
    if (q == 0) atomicAdd(&red[lr], esum + bsum);   // bsum is wave-uniform: add once
    __syncthreads();
    if (tid < BT) atomicAdd(&out[b0i + tid], red[tid]);
}

extern "C" void kernel_launch(void* const* d_in, const int* in_sizes, int n_in,
                              void* d_out, int out_size, void* d_ws, size_t ws_size,
                              hipStream_t stream) {
    const float* x  = (const float*)d_in[0];
    const int*   an = (const int*)d_in[1];
    const float* w0 = (const float*)d_in[2];
    const float* b0 = (const float*)d_in[3];
    const float* w1 = (const float*)d_in[4];
    const float* b1 = (const float*)d_in[5];
    const float* w2 = (const float*)d_in[6];
    const float* b2 = (const float*)d_in[7];
    float* out = (float*)d_out;

    hipMemsetAsync(out, 0, B_ * sizeof(float), stream);  // out accumulated via atomics
    dim3 grid(N_ / NCHUNK, B_ / BT);                     // (32, 32) = 1024 blocks
    bpnn_kernel<<<grid, 256, 0, stream>>>(x, an, w0, b0, w1, b1, w2, b2, out);
}

// Round 2
// 397.513 us; speedup vs baseline: 1.1284x; 1.1284x over previous
//
#include <hip/hip_runtime.h>
#include <hip/hip_bf16.h>

// BPNN: B=512, N=2048, F=64, T=4, H1=64, H2=32.
// out[b] = sum_n MLP_{t[n]}(x[b,n,:]), MLP = silu(W0 x+b0) -> silu(W1 h+b1) -> w2.h+b2
//
// R5: despill + global type-sort.
//  - R4's counters showed WRITE_SIZE=96MB, VGPR=84: the weight-fragment arrays
//    were demoted to scratch (conditional lambda stores in the hot loop).
//    Fix: individually named fragment registers, loaded unconditionally at the
//    top of a run loop (preheader stores, inner loop read-only).
//  - One-wave prepass counting-sorts the GLOBAL atom list by type into d_ws
//    (types depend only on n). Waves take 16 consecutive sorted atoms:
//    perfectly balanced, ~97% single-type waves (~1.03 fragment loads/wave),
//    no per-block LDS sort, no sort barriers.
//  - 2-deep x staging kept (register shift A<=B), NCHUNK=64 (1024 blocks).
// MFMA orientation: D = W * x^T (A-frag == B-frag lane mapping, verified R2).

#define B_ 512
#define N_ 2048
#define F_ 64
#define T_ 4
#define H1_ 64
#define H2_ 32

#define BT 16          // b-tile (MFMA N dim)
#define WAVES 4
#define NCHUNK 64      // sorted atoms per block
#define SLICE (NCHUNK / WAVES)   // 16 atoms per wave, always balanced

typedef __attribute__((ext_vector_type(8))) short bf16x8;
typedef __attribute__((ext_vector_type(4))) short bf16x4;
typedef __attribute__((ext_vector_type(4))) float f32x4;

__device__ inline float silu_f(float v) {
    return v * __builtin_amdgcn_rcpf(1.0f + __expf(-v));
}

__device__ inline bf16x8 pack8(float4 a, float4 b) {
    union { __hip_bfloat162 h[4]; bf16x8 v; } u;
    u.h[0] = __float22bfloat162_rn({a.x, a.y});
    u.h[1] = __float22bfloat162_rn({a.z, a.w});
    u.h[2] = __float22bfloat162_rn({b.x, b.y});
    u.h[3] = __float22bfloat162_rn({b.z, b.w});
    return u.v;
}

__device__ inline bf16x4 pack4(float a, float b, float c, float d) {
    union { __hip_bfloat162 h[2]; bf16x4 v; } u;
    u.h[0] = __float22bfloat162_rn({a, b});
    u.h[1] = __float22bfloat162_rn({c, d});
    return u.v;
}

__device__ inline float bf_at(bf16x4 v, int r) {
    union { bf16x4 v; __hip_bfloat16 h[4]; } u; u.v = v;
    return __bfloat162float(u.h[r]);
}

// ---- prepass: one wave, ordered counting sort of an[] by type -> (t<<16)|n ----
__global__ void sort_atoms(const int* __restrict__ an, int* __restrict__ sorted) {
    const int lane = threadIdx.x;
    int v[32];
#pragma unroll
    for (int c = 0; c < 32; ++c) v[c] = an[c * 64 + lane];

    int c0 = 0, c1 = 0, c2 = 0;
#pragma unroll
    for (int c = 0; c < 32; ++c) {
        c0 += __popcll(__ballot(v[c] == 0));
        c1 += __popcll(__ballot(v[c] == 1));
        c2 += __popcll(__ballot(v[c] == 2));
    }
    int base0 = 0, base1 = c0, base2 = c0 + c1, base3 = c0 + c1 + c2;
    const unsigned long long mb = (1ull << lane) - 1ull;
#pragma unroll
    for (int c = 0; c < 32; ++c) {
        const int t = v[c];
        unsigned long long m0 = __ballot(t == 0);
        unsigned long long m1 = __ballot(t == 1);
        unsigned long long m2 = __ballot(t == 2);
        unsigned long long m3 = __ballot(t == 3);
        int pos;
        if (t == 0)      pos = base0 + (int)__popcll(m0 & mb);
        else if (t == 1) pos = base1 + (int)__popcll(m1 & mb);
        else if (t == 2) pos = base2 + (int)__popcll(m2 & mb);
        else             pos = base3 + (int)__popcll(m3 & mb);
        sorted[pos] = (t << 16) | (c * 64 + lane);
        base0 += (int)__popcll(m0); base1 += (int)__popcll(m1);
        base2 += (int)__popcll(m2); base3 += (int)__popcll(m3);
    }
}

__global__ __launch_bounds__(256, 3) void bpnn_kernel(
    const float* __restrict__ x, const int* __restrict__ sorted,
    const float* __restrict__ w0, const float* __restrict__ b0,
    const float* __restrict__ w1, const float* __restrict__ b1,
    const float* __restrict__ w2, const float* __restrict__ b2,
    float* __restrict__ out)
{
    __shared__ __align__(16) __hip_bfloat16 trb[WAVES][BT][68]; // 8704 B transpose buf [b][h]
    __shared__ float red[BT];

    const int tid  = threadIdx.x;
    const int wave = tid >> 6;
    const int lane = tid & 63;
    const int lr   = lane & 15;      // b-col (B,C) / row (A)
    const int q    = lane >> 4;      // quad
    const int b0i  = blockIdx.y * BT;

    if (tid < BT) red[tid] = 0.0f;
    __syncthreads();

    const float* xb_ = x + (size_t)(b0i + lr) * (N_ * F_) + q * 8;
    __hip_bfloat16* trbw = &trb[wave][lr][0];

    const int s0 = blockIdx.x * NCHUNK + wave * SLICE;
    const int s1 = s0 + SLICE;

    float esum0 = 0.f, esum1 = 0.f, bsum = 0.f;

    // fragment registers: individually named -> guaranteed registers
    bf16x8 aw000, aw001, aw010, aw011, aw020, aw021, aw030, aw031;
    bf16x8 aw100, aw101, aw110, aw111;
    bf16x4 b0f0, b0f1, b0f2, b0f3, b1f0, b1f1, w2f0, w2f1;
    float b2c = 0.f;

    // 2-deep x staging
    int p = s0;
    int id0 = __builtin_amdgcn_readfirstlane(sorted[p]);
    int id1 = __builtin_amdgcn_readfirstlane(sorted[p + 1]);
    float4 sa0, sa1, sa2, sa3, sb0, sb1, sb2, sb3;
    {
        const float4* pA = reinterpret_cast<const float4*>(xb_ + (id0 & 0xFFFF) * F_);
        sa0 = pA[0]; sa1 = pA[1]; sa2 = pA[8]; sa3 = pA[9];
        const float4* pB = reinterpret_cast<const float4*>(xb_ + (id1 & 0xFFFF) * F_);
        sb0 = pB[0]; sb1 = pB[1]; sb2 = pB[8]; sb3 = pB[9];
    }

    while (p < s1) {
        const int t = id0 >> 16;
        // ---- load fragments for type t (unconditional, top of run) ----
        {
            const float* wb = w0 + t * (H1_ * F_) + lr * F_ + q * 8;
            const float4* pw;
            pw = reinterpret_cast<const float4*>(wb +  0 * F_ +  0); aw000 = pack8(pw[0], pw[1]);
            pw = reinterpret_cast<const float4*>(wb +  0 * F_ + 32); aw001 = pack8(pw[0], pw[1]);
            pw = reinterpret_cast<const float4*>(wb + 16 * F_ +  0); aw010 = pack8(pw[0], pw[1]);
            pw = reinterpret_cast<const float4*>(wb + 16 * F_ + 32); aw011 = pack8(pw[0], pw[1]);
            pw = reinterpret_cast<const float4*>(wb + 32 * F_ +  0); aw020 = pack8(pw[0], pw[1]);
            pw = reinterpret_cast<const float4*>(wb + 32 * F_ + 32); aw021 = pack8(pw[0], pw[1]);
            pw = reinterpret_cast<const float4*>(wb + 48 * F_ +  0); aw030 = pack8(pw[0], pw[1]);
            pw = reinterpret_cast<const float4*>(wb + 48 * F_ + 32); aw031 = pack8(pw[0], pw[1]);
            const float* wc = w1 + t * (H2_ * H1_) + lr * H1_ + q * 8;
            pw = reinterpret_cast<const float4*>(wc +  0 * H1_ +  0); aw100 = pack8(pw[0], pw[1]);
            pw = reinterpret_cast<const float4*>(wc +  0 * H1_ + 32); aw101 = pack8(pw[0], pw[1]);
            pw = reinterpret_cast<const float4*>(wc + 16 * H1_ +  0); aw110 = pack8(pw[0], pw[1]);
            pw = reinterpret_cast<const float4*>(wc + 16 * H1_ + 32); aw111 = pack8(pw[0], pw[1]);
            float4 v;
            v = *reinterpret_cast<const float4*>(b0 + t * H1_ +  0 + q * 4); b0f0 = pack4(v.x, v.y, v.z, v.w);
            v = *reinterpret_cast<const float4*>(b0 + t * H1_ + 16 + q * 4); b0f1 = pack4(v.x, v.y, v.z, v.w);
            v = *reinterpret_cast<const float4*>(b0 + t * H1_ + 32 + q * 4); b0f2 = pack4(v.x, v.y, v.z, v.w);
            v = *reinterpret_cast<const float4*>(b0 + t * H1_ + 48 + q * 4); b0f3 = pack4(v.x, v.y, v.z, v.w);
            v = *reinterpret_cast<const float4*>(b1 + t * H2_ +  0 + q * 4); b1f0 = pack4(v.x, v.y, v.z, v.w);
            v = *reinterpret_cast<const float4*>(b1 + t * H2_ + 16 + q * 4); b1f1 = pack4(v.x, v.y, v.z, v.w);
            v = *reinterpret_cast<const float4*>(w2 + t * H2_ +  0 + q * 4); w2f0 = pack4(v.x, v.y, v.z, v.w);
            v = *reinterpret_cast<const float4*>(w2 + t * H2_ + 16 + q * 4); w2f1 = pack4(v.x, v.y, v.z, v.w);
            b2c = b2[t];
        }

        // ---- inner loop over this type run (fragments read-only) ----
        for (;;) {
            bf16x8 xf0 = pack8(sa0, sa1);            // data prefetched >=2 atoms ago
            bf16x8 xf1 = pack8(sa2, sa3);
            sa0 = sb0; sa1 = sb1; sa2 = sb2; sa3 = sb3;   // shift pipeline A <= B
            int pn = p + 2;
            int idn = id1;
            if (pn < s1) idn = __builtin_amdgcn_readfirstlane(sorted[pn]);
            {
                const float4* pB = reinterpret_cast<const float4*>(xb_ + (idn & 0xFFFF) * F_);
                sb0 = pB[0]; sb1 = pB[1]; sb2 = pB[8]; sb3 = pB[9];
            }
            bsum += b2c;

            // ---- layer 0: D0[64h x 16b] = W0_t * x^T ----
            f32x4 acc0 = {0.f,0.f,0.f,0.f}, acc1 = {0.f,0.f,0.f,0.f};
            f32x4 acc2 = {0.f,0.f,0.f,0.f}, acc3 = {0.f,0.f,0.f,0.f};
            acc0 = __builtin_amdgcn_mfma_f32_16x16x32_bf16(aw000, xf0, acc0, 0, 0, 0);
            acc0 = __builtin_amdgcn_mfma_f32_16x16x32_bf16(aw001, xf1, acc0, 0, 0, 0);
            acc1 = __builtin_amdgcn_mfma_f32_16x16x32_bf16(aw010, xf0, acc1, 0, 0, 0);
            acc1 = __builtin_amdgcn_mfma_f32_16x16x32_bf16(aw011, xf1, acc1, 0, 0, 0);
            acc2 = __builtin_amdgcn_mfma_f32_16x16x32_bf16(aw020, xf0, acc2, 0, 0, 0);
            acc2 = __builtin_amdgcn_mfma_f32_16x16x32_bf16(aw021, xf1, acc2, 0, 0, 0);
            acc3 = __builtin_amdgcn_mfma_f32_16x16x32_bf16(aw030, xf0, acc3, 0, 0, 0);
            acc3 = __builtin_amdgcn_mfma_f32_16x16x32_bf16(aw031, xf1, acc3, 0, 0, 0);

            // bias + silu; lane holds h = nt*16 + q*4 + r, b = lr
            {
                float v0 = silu_f(acc0[0] + bf_at(b0f0, 0));
                float v1 = silu_f(acc0[1] + bf_at(b0f0, 1));
                float v2 = silu_f(acc0[2] + bf_at(b0f0, 2));
                float v3 = silu_f(acc0[3] + bf_at(b0f0, 3));
                *reinterpret_cast<bf16x4*>(trbw +  0 + q * 4) = pack4(v0, v1, v2, v3);
                v0 = silu_f(acc1[0] + bf_at(b0f1, 0));
                v1 = silu_f(acc1[1] + bf_at(b0f1, 1));
                v2 = silu_f(acc1[2] + bf_at(b0f1, 2));
                v3 = silu_f(acc1[3] + bf_at(b0f1, 3));
                *reinterpret_cast<bf16x4*>(trbw + 16 + q * 4) = pack4(v0, v1, v2, v3);
                v0 = silu_f(acc2[0] + bf_at(b0f2, 0));
                v1 = silu_f(acc2[1] + bf_at(b0f2, 1));
                v2 = silu_f(acc2[2] + bf_at(b0f2, 2));
                v3 = silu_f(acc2[3] + bf_at(b0f2, 3));
                *reinterpret_cast<bf16x4*>(trbw + 32 + q * 4) = pack4(v0, v1, v2, v3);
                v0 = silu_f(acc3[0] + bf_at(b0f3, 0));
                v1 = silu_f(acc3[1] + bf_at(b0f3, 1));
                v2 = silu_f(acc3[2] + bf_at(b0f3, 2));
                v3 = silu_f(acc3[3] + bf_at(b0f3, 3));
                *reinterpret_cast<bf16x4*>(trbw + 48 + q * 4) = pack4(v0, v1, v2, v3);
            }
            __builtin_amdgcn_wave_barrier();  // order LDS write->read (per-wave buffer)

            bf16x8 hb0 = *reinterpret_cast<const bf16x8*>(trbw + q * 8);
            bf16x8 hb1 = *reinterpret_cast<const bf16x8*>(trbw + 32 + q * 8);
            __builtin_amdgcn_wave_barrier();

            // ---- layer 1: D1[32g x 16b] = W1_t * h1 ----
            f32x4 acB0 = {0.f,0.f,0.f,0.f}, acB1 = {0.f,0.f,0.f,0.f};
            acB0 = __builtin_amdgcn_mfma_f32_16x16x32_bf16(aw100, hb0, acB0, 0, 0, 0);
            acB0 = __builtin_amdgcn_mfma_f32_16x16x32_bf16(aw101, hb1, acB0, 0, 0, 0);
            acB1 = __builtin_amdgcn_mfma_f32_16x16x32_bf16(aw110, hb0, acB1, 0, 0, 0);
            acB1 = __builtin_amdgcn_mfma_f32_16x16x32_bf16(aw111, hb1, acB1, 0, 0, 0);

            // ---- layer 2: lane accumulates w2[g]*silu(.) over its 8 g ----
#pragma unroll
            for (int r = 0; r < 4; ++r) {
                esum0 += silu_f(acB0[r] + bf_at(b1f0, r)) * bf_at(w2f0, r);
                esum1 += silu_f(acB1[r] + bf_at(b1f1, r)) * bf_at(w2f1, r);
            }

            ++p;
            id0 = id1; id1 = idn;
            if (p >= s1 || (id0 >> 16) != t) break;
        }
    }

    // reduce esum over the 4 quads holding the same b (lane bits 4-5)
    float esum = esum0 + esum1;
    esum += __shfl_xor(esum, 16);
    esum += __shfl_xor(esum, 32);
    if (q == 0) atomicAdd(&red[lr], esum + bsum);   // bsum wave-uniform: add once per quad0
    __syncthreads();
    if (tid < BT) atomicAdd(&out[b0i + tid], red[tid]);
}

extern "C" void kernel_launch(void* const* d_in, const int* in_sizes, int n_in,
                              void* d_out, int out_size, void* d_ws, size_t ws_size,
                              hipStream_t stream) {
    const float* x  = (const float*)d_in[0];
    const int*   an = (const int*)d_in[1];
    const float* w0 = (const float*)d_in[2];
    const float* b0 = (const float*)d_in[3];
    const float* w1 = (const float*)d_in[4];
    const float* b1 = (const float*)d_in[5];
    const float* w2 = (const float*)d_in[6];
    const float* b2 = (const float*)d_in[7];
    float* out = (float*)d_out;
    int* sorted = (int*)d_ws;            // 2048 ints = 8 KB

    hipMemsetAsync(out, 0, B_ * sizeof(float), stream);   // out accumulated via atomics
    sort_atoms<<<1, 64, 0, stream>>>(an, sorted);
    dim3 grid(N_ / NCHUNK, B_ / BT);                      // (32, 32) = 1024 blocks
    bpnn_kernel<<<grid, 256, 0, stream>>>(x, sorted, w0, b0, w1, b1, w2, b2, out);
}

// Round 3
// 386.376 us; speedup vs baseline: 1.1610x; 1.0288x over previous
//
#include <hip/hip_runtime.h>
#include <hip/hip_bf16.h>

// BPNN: B=512, N=2048, F=64, T=4, H1=64, H2=32.
// out[b] = sum_n MLP_{t[n]}(x[b,n,:]), MLP = silu(W0 x+b0) -> silu(W1 h+b1) -> w2.h+b2
//
// R6: drop d_ws (the harness re-poisons the 1-GiB workspace every iteration:
// 160 us fillBuffer at 83% HBM peak dominated R5's top-5). The global sort
// prepass is replaced by a per-block, in-register ballot counting sort:
// NCHUNK=64 == wave width, so each wave computes every atom's sorted rank
// with 4 ballots + prefix popcounts; wave 0 writes sidx[64] to LDS. No
// atomics, no extra kernel, no workspace.
//  - R5 despill kept: individually named fragment registers, loaded
//    unconditionally at the top of each type-run (preheader stores only).
//  - 2-deep x staging kept (register shift A<=B), NCHUNK=64 (1024 blocks).
// MFMA orientation: D = W * x^T (A-frag == B-frag lane mapping, verified R2).

#define B_ 512
#define N_ 2048
#define F_ 64
#define T_ 4
#define H1_ 64
#define H2_ 32

#define BT 16          // b-tile (MFMA N dim)
#define WAVES 4
#define NCHUNK 64      // atoms per block == wave width
#define SLICE (NCHUNK / WAVES)   // 16 atoms per wave, always balanced

typedef __attribute__((ext_vector_type(8))) short bf16x8;
typedef __attribute__((ext_vector_type(4))) short bf16x4;
typedef __attribute__((ext_vector_type(4))) float f32x4;

__device__ inline float silu_f(float v) {
    return v * __builtin_amdgcn_rcpf(1.0f + __expf(-v));
}

__device__ inline bf16x8 pack8(float4 a, float4 b) {
    union { __hip_bfloat162 h[4]; bf16x8 v; } u;
    u.h[0] = __float22bfloat162_rn({a.x, a.y});
    u.h[1] = __float22bfloat162_rn({a.z, a.w});
    u.h[2] = __float22bfloat162_rn({b.x, b.y});
    u.h[3] = __float22bfloat162_rn({b.z, b.w});
    return u.v;
}

__device__ inline bf16x4 pack4(float a, float b, float c, float d) {
    union { __hip_bfloat162 h[2]; bf16x4 v; } u;
    u.h[0] = __float22bfloat162_rn({a, b});
    u.h[1] = __float22bfloat162_rn({c, d});
    return u.v;
}

__device__ inline float bf_at(bf16x4 v, int r) {
    union { bf16x4 v; __hip_bfloat16 h[4]; } u; u.v = v;
    return __bfloat162float(u.h[r]);
}

__global__ __launch_bounds__(256, 3) void bpnn_kernel(
    const float* __restrict__ x, const int* __restrict__ an,
    const float* __restrict__ w0, const float* __restrict__ b0,
    const float* __restrict__ w1, const float* __restrict__ b1,
    const float* __restrict__ w2, const float* __restrict__ b2,
    float* __restrict__ out)
{
    __shared__ __align__(16) __hip_bfloat16 trb[WAVES][BT][68]; // 8704 B transpose buf [b][h]
    __shared__ int sidx[NCHUNK];   // type-sorted, packed (type<<8)|n_local
    __shared__ float red[BT];

    const int tid  = threadIdx.x;
    const int wave = tid >> 6;
    const int lane = tid & 63;
    const int lr   = lane & 15;      // b-col (B,C) / row (A)
    const int q    = lane >> 4;      // quad
    const int b0i  = blockIdx.y * BT;
    const int n0   = blockIdx.x * NCHUNK;

    if (tid < BT) red[tid] = 0.0f;

    // ---- in-register ballot counting sort of the block's 64 atoms ----
    {
        const int t = an[n0 + lane];
        unsigned long long m0 = __ballot(t == 0);
        unsigned long long m1 = __ballot(t == 1);
        unsigned long long m2 = __ballot(t == 2);
        unsigned long long m3 = __ballot(t == 3);
        const int base1 = (int)__popcll(m0);
        const int base2 = base1 + (int)__popcll(m1);
        const int base3 = base2 + (int)__popcll(m2);
        const unsigned long long mb = (1ull << lane) - 1ull;
        int r;
        if (t == 0)      r = (int)__popcll(m0 & mb);
        else if (t == 1) r = base1 + (int)__popcll(m1 & mb);
        else if (t == 2) r = base2 + (int)__popcll(m2 & mb);
        else             r = base3 + (int)__popcll(m3 & mb);
        if (wave == 0) sidx[r] = (t << 8) | lane;
    }
    __syncthreads();

    const float* xb_ = x + (size_t)(b0i + lr) * (N_ * F_) + (size_t)n0 * F_ + q * 8;
    __hip_bfloat16* trbw = &trb[wave][lr][0];

    const int s0 = wave * SLICE;
    const int s1 = s0 + SLICE;

    float esum0 = 0.f, esum1 = 0.f, bsum = 0.f;

    // fragment registers: individually named -> guaranteed registers
    bf16x8 aw000, aw001, aw010, aw011, aw020, aw021, aw030, aw031;
    bf16x8 aw100, aw101, aw110, aw111;
    bf16x4 b0f0, b0f1, b0f2, b0f3, b1f0, b1f1, w2f0, w2f1;
    float b2c = 0.f;

    // 2-deep x staging
    int p = s0;
    int id0 = __builtin_amdgcn_readfirstlane(sidx[p]);
    int id1 = __builtin_amdgcn_readfirstlane(sidx[p + 1]);
    float4 sa0, sa1, sa2, sa3, sb0, sb1, sb2, sb3;
    {
        const float4* pA = reinterpret_cast<const float4*>(xb_ + (id0 & 0xFF) * F_);
        sa0 = pA[0]; sa1 = pA[1]; sa2 = pA[8]; sa3 = pA[9];
        const float4* pB = reinterpret_cast<const float4*>(xb_ + (id1 & 0xFF) * F_);
        sb0 = pB[0]; sb1 = pB[1]; sb2 = pB[8]; sb3 = pB[9];
    }

    while (p < s1) {
        const int t = id0 >> 8;
        // ---- load fragments for type t (unconditional, top of run) ----
        {
            const float* wb = w0 + t * (H1_ * F_) + lr * F_ + q * 8;
            const float4* pw;
            pw = reinterpret_cast<const float4*>(wb +  0 * F_ +  0); aw000 = pack8(pw[0], pw[1]);
            pw = reinterpret_cast<const float4*>(wb +  0 * F_ + 32); aw001 = pack8(pw[0], pw[1]);
            pw = reinterpret_cast<const float4*>(wb + 16 * F_ +  0); aw010 = pack8(pw[0], pw[1]);
            pw = reinterpret_cast<const float4*>(wb + 16 * F_ + 32); aw011 = pack8(pw[0], pw[1]);
            pw = reinterpret_cast<const float4*>(wb + 32 * F_ +  0); aw020 = pack8(pw[0], pw[1]);
            pw = reinterpret_cast<const float4*>(wb + 32 * F_ + 32); aw021 = pack8(pw[0], pw[1]);
            pw = reinterpret_cast<const float4*>(wb + 48 * F_ +  0); aw030 = pack8(pw[0], pw[1]);
            pw = reinterpret_cast<const float4*>(wb + 48 * F_ + 32); aw031 = pack8(pw[0], pw[1]);
            const float* wc = w1 + t * (H2_ * H1_) + lr * H1_ + q * 8;
            pw = reinterpret_cast<const float4*>(wc +  0 * H1_ +  0); aw100 = pack8(pw[0], pw[1]);
            pw = reinterpret_cast<const float4*>(wc +  0 * H1_ + 32); aw101 = pack8(pw[0], pw[1]);
            pw = reinterpret_cast<const float4*>(wc + 16 * H1_ +  0); aw110 = pack8(pw[0], pw[1]);
            pw = reinterpret_cast<const float4*>(wc + 16 * H1_ + 32); aw111 = pack8(pw[0], pw[1]);
            float4 v;
            v = *reinterpret_cast<const float4*>(b0 + t * H1_ +  0 + q * 4); b0f0 = pack4(v.x, v.y, v.z, v.w);
            v = *reinterpret_cast<const float4*>(b0 + t * H1_ + 16 + q * 4); b0f1 = pack4(v.x, v.y, v.z, v.w);
            v = *reinterpret_cast<const float4*>(b0 + t * H1_ + 32 + q * 4); b0f2 = pack4(v.x, v.y, v.z, v.w);
            v = *reinterpret_cast<const float4*>(b0 + t * H1_ + 48 + q * 4); b0f3 = pack4(v.x, v.y, v.z, v.w);
            v = *reinterpret_cast<const float4*>(b1 + t * H2_ +  0 + q * 4); b1f0 = pack4(v.x, v.y, v.z, v.w);
            v = *reinterpret_cast<const float4*>(b1 + t * H2_ + 16 + q * 4); b1f1 = pack4(v.x, v.y, v.z, v.w);
            v = *reinterpret_cast<const float4*>(w2 + t * H2_ +  0 + q * 4); w2f0 = pack4(v.x, v.y, v.z, v.w);
            v = *reinterpret_cast<const float4*>(w2 + t * H2_ + 16 + q * 4); w2f1 = pack4(v.x, v.y, v.z, v.w);
            b2c = b2[t];
        }

        // ---- inner loop over this type run (fragments read-only) ----
        for (;;) {
            bf16x8 xf0 = pack8(sa0, sa1);            // data prefetched >=2 atoms ago
            bf16x8 xf1 = pack8(sa2, sa3);
            sa0 = sb0; sa1 = sb1; sa2 = sb2; sa3 = sb3;   // shift pipeline A <= B
            int pn = p + 2;
            int idn = id1;
            if (pn < s1) idn = __builtin_amdgcn_readfirstlane(sidx[pn]);
            {
                const float4* pB = reinterpret_cast<const float4*>(xb_ + (idn & 0xFF) * F_);
                sb0 = pB[0]; sb1 = pB[1]; sb2 = pB[8]; sb3 = pB[9];
            }
            bsum += b2c;

            // ---- layer 0: D0[64h x 16b] = W0_t * x^T ----
            f32x4 acc0 = {0.f,0.f,0.f,0.f}, acc1 = {0.f,0.f,0.f,0.f};
            f32x4 acc2 = {0.f,0.f,0.f,0.f}, acc3 = {0.f,0.f,0.f,0.f};
            acc0 = __builtin_amdgcn_mfma_f32_16x16x32_bf16(aw000, xf0, acc0, 0, 0, 0);
            acc0 = __builtin_amdgcn_mfma_f32_16x16x32_bf16(aw001, xf1, acc0, 0, 0, 0);
            acc1 = __builtin_amdgcn_mfma_f32_16x16x32_bf16(aw010, xf0, acc1, 0, 0, 0);
            acc1 = __builtin_amdgcn_mfma_f32_16x16x32_bf16(aw011, xf1, acc1, 0, 0, 0);
            acc2 = __builtin_amdgcn_mfma_f32_16x16x32_bf16(aw020, xf0, acc2, 0, 0, 0);
            acc2 = __builtin_amdgcn_mfma_f32_16x16x32_bf16(aw021, xf1, acc2, 0, 0, 0);
            acc3 = __builtin_amdgcn_mfma_f32_16x16x32_bf16(aw030, xf0, acc3, 0, 0, 0);
            acc3 = __builtin_amdgcn_mfma_f32_16x16x32_bf16(aw031, xf1, acc3, 0, 0, 0);

            // bias + silu; lane holds h = nt*16 + q*4 + r, b = lr
            {
                float v0 = silu_f(acc0[0] + bf_at(b0f0, 0));
                float v1 = silu_f(acc0[1] + bf_at(b0f0, 1));
                float v2 = silu_f(acc0[2] + bf_at(b0f0, 2));
                float v3 = silu_f(acc0[3] + bf_at(b0f0, 3));
                *reinterpret_cast<bf16x4*>(trbw +  0 + q * 4) = pack4(v0, v1, v2, v3);
                v0 = silu_f(acc1[0] + bf_at(b0f1, 0));
                v1 = silu_f(acc1[1] + bf_at(b0f1, 1));
                v2 = silu_f(acc1[2] + bf_at(b0f1, 2));
                v3 = silu_f(acc1[3] + bf_at(b0f1, 3));
                *reinterpret_cast<bf16x4*>(trbw + 16 + q * 4) = pack4(v0, v1, v2, v3);
                v0 = silu_f(acc2[0] + bf_at(b0f2, 0));
                v1 = silu_f(acc2[1] + bf_at(b0f2, 1));
                v2 = silu_f(acc2[2] + bf_at(b0f2, 2));
                v3 = silu_f(acc2[3] + bf_at(b0f2, 3));
                *reinterpret_cast<bf16x4*>(trbw + 32 + q * 4) = pack4(v0, v1, v2, v3);
                v0 = silu_f(acc3[0] + bf_at(b0f3, 0));
                v1 = silu_f(acc3[1] + bf_at(b0f3, 1));
                v2 = silu_f(acc3[2] + bf_at(b0f3, 2));
                v3 = silu_f(acc3[3] + bf_at(b0f3, 3));
                *reinterpret_cast<bf16x4*>(trbw + 48 + q * 4) = pack4(v0, v1, v2, v3);
            }
            __builtin_amdgcn_wave_barrier();  // order LDS write->read (per-wave buffer)

            bf16x8 hb0 = *reinterpret_cast<const bf16x8*>(trbw + q * 8);
            bf16x8 hb1 = *reinterpret_cast<const bf16x8*>(trbw + 32 + q * 8);
            __builtin_amdgcn_wave_barrier();

            // ---- layer 1: D1[32g x 16b] = W1_t * h1 ----
            f32x4 acB0 = {0.f,0.f,0.f,0.f}, acB1 = {0.f,0.f,0.f,0.f};
            acB0 = __builtin_amdgcn_mfma_f32_16x16x32_bf16(aw100, hb0, acB0, 0, 0, 0);
            acB0 = __builtin_amdgcn_mfma_f32_16x16x32_bf16(aw101, hb1, acB0, 0, 0, 0);
            acB1 = __builtin_amdgcn_mfma_f32_16x16x32_bf16(aw110, hb0, acB1, 0, 0, 0);
            acB1 = __builtin_amdgcn_mfma_f32_16x16x32_bf16(aw111, hb1, acB1, 0, 0, 0);

            // ---- layer 2: lane accumulates w2[g]*silu(.) over its 8 g ----
#pragma unroll
            for (int r = 0; r < 4; ++r) {
                esum0 += silu_f(acB0[r] + bf_at(b1f0, r)) * bf_at(w2f0, r);
                esum1 += silu_f(acB1[r] + bf_at(b1f1, r)) * bf_at(w2f1, r);
            }

            ++p;
            id0 = id1; id1 = idn;
            if (p >= s1 || (id0 >> 8) != t) break;
        }
    }

    // reduce esum over the 4 quads holding the same b (lane bits 4-5)
    float esum = esum0 + esum1;
    esum += __shfl_xor(esum, 16);
    esum += __shfl_xor(esum, 32);
    if (q == 0) atomicAdd(&red[lr], esum + bsum);   // bsum wave-uniform: add once per quad0
    __syncthreads();
    if (tid < BT) atomicAdd(&out[b0i + tid], red[tid]);
}

extern "C" void kernel_launch(void* const* d_in, const int* in_sizes, int n_in,
                              void* d_out, int out_size, void* d_ws, size_t ws_size,
                              hipStream_t stream) {
    const float* x  = (const float*)d_in[0];
    const int*   an = (const int*)d_in[1];
    const float* w0 = (const float*)d_in[2];
    const float* b0 = (const float*)d_in[3];
    const float* w1 = (const float*)d_in[4];
    const float* b1 = (const float*)d_in[5];
    const float* w2 = (const float*)d_in[6];
    const float* b2 = (const float*)d_in[7];
    float* out = (float*)d_out;

    hipMemsetAsync(out, 0, B_ * sizeof(float), stream);   // out accumulated via atomics
    dim3 grid(N_ / NCHUNK, B_ / BT);                      // (32, 32) = 1024 blocks
    bpnn_kernel<<<grid, 256, 0, stream>>>(x, an, w0, b0, w1, b1, w2, b2, out);
}